// Round 2
// baseline (675.364 us; speedup 1.0000x reference)
//
#include <hip/hip_runtime.h>
#include <hip/hip_bf16.h>

#define V    100000
#define EMB  128
#define REG  7
#define NC   20
#define ML   512
#define BB   64
#define RAD  3
#define ENT  506      // ML - 2*RAD
#define TI   32       // entries per block-chunk
#define NBLK 16       // chunks per batch row (16*32 = 512 >= 506)

// Fused kernel. Phase 1: each of 1024 blocks computes a partial noi[128] for
// (b, 32-entry chunk). Phase 2: the 16th-finishing block of each b (atomic
// counter, no spinning -> safe under any dispatch order) reduces the 16
// partials in FIXED order (deterministic) and runs the MLP + softmax/argmax.
//
// Semantics (reshape trap): E index for (b,i,j) is t=i*7+j;
// word = train[b, (t%506) + (t/506)]; region row = train[b, i+3], slice j.
__global__ __launch_bounds__(256) void fused_kernel(
    const int*   __restrict__ train,
    const float* __restrict__ Wr,
    const float* __restrict__ Ww,
    const float* __restrict__ W1,
    const float* __restrict__ b1,
    const float* __restrict__ W2,
    const float* __restrict__ b2,
    float*       __restrict__ partial,
    int*         __restrict__ ctr,
    float*       __restrict__ out)
{
    __shared__ int   idx_lds[TI * 8];   // [il][0]=region row, [1..7]=word rows
    __shared__ float red[4][EMB];
    __shared__ int   is_last;
    __shared__ float noi[EMB];
    __shared__ float hbuf[2 * ML];
    __shared__ float lg[NC];

    const int blk = blockIdx.x;          // 0 .. 1023
    const int b   = blk >> 4;
    const int i0  = (blk & 15) * TI;
    const int tid = threadIdx.x;

    // ---- index precompute: 256 slots == 256 threads ----
    {
        const int il  = tid >> 3;
        const int sub = tid & 7;
        const int i   = i0 + il;
        int v = 0;
        if (i < ENT) {
            if (sub == 0) {
                v = train[b * ML + i + RAD];
            } else {
                const int t = i * REG + (sub - 1);
                const int r = t / ENT;               // const divisor -> magic mul
                const int e = t - r * ENT;
                v = train[b * ML + e + r];
            }
        }
        idx_lds[tid] = v;
    }
    __syncthreads();

    const int w    = tid >> 6;
    const int lane = tid & 63;
    const int lim  = (ENT - i0 < TI) ? (ENT - i0) : TI;   // 32 or 26; >= 26 > 3

    // ---- phase 1: gather + max_j + sum_i, software-pipelined ----
    float accx = 0.f, accy = 0.f;
    {
        int il = w;
        float2 kv[REG], ev[REG];
        {
            const int base = il * 8;
            const float2* Krow = (const float2*)(Wr + (size_t)idx_lds[base] * (REG * EMB));
            #pragma unroll
            for (int j = 0; j < REG; ++j) {
                kv[j] = Krow[j * 64 + lane];
                ev[j] = ((const float2*)(Ww + (size_t)idx_lds[base + 1 + j] * EMB))[lane];
            }
        }
        while (true) {
            // prefetch next iteration (clamped: harmless L1-hit reload on last)
            const int iln  = (il + 4 < lim) ? (il + 4) : il;
            float2 kn[REG], en[REG];
            {
                const int base = iln * 8;
                const float2* Krow = (const float2*)(Wr + (size_t)idx_lds[base] * (REG * EMB));
                #pragma unroll
                for (int j = 0; j < REG; ++j) {
                    kn[j] = Krow[j * 64 + lane];
                    en[j] = ((const float2*)(Ww + (size_t)idx_lds[base + 1 + j] * EMB))[lane];
                }
            }
            // compute on current
            float mx = kv[0].x * ev[0].x;
            float my = kv[0].y * ev[0].y;
            #pragma unroll
            for (int j = 1; j < REG; ++j) {
                mx = fmaxf(mx, kv[j].x * ev[j].x);
                my = fmaxf(my, kv[j].y * ev[j].y);
            }
            accx += mx;
            accy += my;
            if (il + 4 >= lim) break;
            il += 4;
            #pragma unroll
            for (int j = 0; j < REG; ++j) { kv[j] = kn[j]; ev[j] = en[j]; }
        }
    }

    red[w][2 * lane]     = accx;
    red[w][2 * lane + 1] = accy;
    __syncthreads();
    if (tid < EMB) {
        const float s = red[0][tid] + red[1][tid] + red[2][tid] + red[3][tid];
        partial[(size_t)blk * EMB + tid] = s;
    }
    __threadfence();            // release: partial visible device-wide
    __syncthreads();
    if (tid == 0) {
        const int old = atomicAdd(&ctr[b], 1);      // device-scope
        is_last = (old == NBLK - 1) ? 1 : 0;
    }
    __syncthreads();
    if (!is_last) return;
    __threadfence();            // acquire: see other blocks' partials

    // ---- phase 2 (one block per b): reduce 16 partials -> MLP ----
    if (tid < EMB) {
        float s = 0.f;
        #pragma unroll
        for (int k = 0; k < NBLK; ++k)
            s += partial[(size_t)(b * NBLK + k) * EMB + tid];
        noi[tid] = s;
    }
    __syncthreads();

    float h0 = b1[tid], h1 = b1[tid + 256], h2 = b1[tid + 512], h3 = b1[tid + 768];
    for (int k = 0; k < EMB; ++k) {
        const float nk = noi[k];
        const float* row = W1 + k * (2 * ML);
        h0 = fmaf(nk, row[tid],       h0);
        h1 = fmaf(nk, row[tid + 256], h1);
        h2 = fmaf(nk, row[tid + 512], h2);
        h3 = fmaf(nk, row[tid + 768], h3);
    }
    hbuf[tid]       = fmaxf(h0, 0.f);
    hbuf[tid + 256] = fmaxf(h1, 0.f);
    hbuf[tid + 512] = fmaxf(h2, 0.f);
    hbuf[tid + 768] = fmaxf(h3, 0.f);
    __syncthreads();

    for (int c = w; c < NC; c += 4) {
        float p = 0.f;
        #pragma unroll 4
        for (int k = lane; k < 2 * ML; k += 64)
            p = fmaf(hbuf[k], W2[k * NC + c], p);
        for (int off = 32; off; off >>= 1)
            p += __shfl_down(p, off);
        if (lane == 0) lg[c] = p + b2[c];
    }
    __syncthreads();

    if (tid == 0) {
        float mx = lg[0];
        for (int c = 1; c < NC; ++c) mx = fmaxf(mx, lg[c]);
        float pr[NC];
        float s = 0.f;
        for (int c = 0; c < NC; ++c) { pr[c] = __expf(lg[c] - mx); s += pr[c]; }
        const float inv = 1.f / s;
        int am = 0; float best = lg[0];
        for (int c = 1; c < NC; ++c) if (lg[c] > best) { best = lg[c]; am = c; }
        for (int c = 0; c < NC; ++c) {
            out[b * NC + c]           = lg[c];           // logits
            out[BB * NC + b * NC + c] = pr[c] * inv;     // prob
        }
        out[2 * BB * NC + b] = (float)am;                // cls (as float)
    }
}

extern "C" void kernel_launch(void* const* d_in, const int* in_sizes, int n_in,
                              void* d_out, int out_size, void* d_ws, size_t ws_size,
                              hipStream_t stream) {
    const int*   train = (const int*)  d_in[0];
    const float* Wr    = (const float*)d_in[1];
    const float* Ww    = (const float*)d_in[2];
    const float* W1    = (const float*)d_in[3];
    const float* b1    = (const float*)d_in[4];
    const float* W2    = (const float*)d_in[5];
    const float* b2    = (const float*)d_in[6];
    float* out     = (float*)d_out;
    float* partial = (float*)d_ws;                               // 512 KB
    int*   ctr     = (int*)((char*)d_ws + (size_t)BB * NBLK * EMB * sizeof(float));

    // zero the 64 completion counters (memset node: graph-capture legal)
    hipMemsetAsync(ctr, 0, BB * sizeof(int), stream);

    hipLaunchKernelGGL(fused_kernel, dim3(BB * NBLK), dim3(256), 0, stream,
                       train, Wr, Ww, W1, b1, W2, b2, partial, ctr, out);
}

// Round 3
// 471.956 us; speedup vs baseline: 1.4310x; 1.4310x over previous
//
#include <hip/hip_runtime.h>
#include <hip/hip_bf16.h>

#define V    100000
#define EMB  128
#define REG  7
#define NC   20
#define ML   512
#define BB   64
#define RAD  3
#define ENT  506      // ML - 2*RAD
#define NB2  127      // ceil(506/4) chunks of 4 entries per batch row

// Kernel 1: one wave per entry (b, i). Straight-line gather: 8 uniform index
// loads -> 14 independent float2 loads (64 lanes x 8B = one 512B row segment
// each, fully coalesced) -> per-channel max over j -> 4-wave LDS reduce ->
// one partial[128] per block. No loops around the loads: the compiler emits
// one load batch + one waitcnt, so memory-level parallelism comes from TLP
// (up to 32 waves/CU x 7KB in flight each >> 9.2KB/CU needed for 6.3 TB/s).
//
// Semantics (reshape trap): E index for (b,i,j) is t=i*7+j;
// word = train[b, (t%506) + (t/506)]; region row = train[b, i+3], slice j.
__global__ __launch_bounds__(256, 4) void noi_kernel(
    const int*   __restrict__ train,
    const float* __restrict__ Wr,
    const float* __restrict__ Ww,
    float*       __restrict__ partial)
{
    __shared__ float red[4][EMB];

    const int b    = blockIdx.y;          // 0..63
    const int c4   = blockIdx.x;          // 0..126 (chunk of 4 entries)
    const int tid  = threadIdx.x;
    const int w    = tid >> 6;
    const int lane = tid & 63;
    const int i    = c4 * 4 + w;

    float mx = 0.f, my = 0.f;
    if (i < ENT) {                         // wave-uniform
        const int* trow = train + b * ML;
        const int  ridx = trow[i + RAD];   // uniform -> scalar load
        int widx[REG];
        #pragma unroll
        for (int j = 0; j < REG; ++j) {
            const int t = i * REG + j;
            const int r = t / ENT;         // const divisor -> magic mul
            const int e = t - r * ENT;
            widx[j] = trow[e + r];         // uniform -> scalar load
        }

        const float2* Kp = (const float2*)(Wr + (size_t)ridx * (REG * EMB));
        float2 kv[REG], ev[REG];
        #pragma unroll
        for (int j = 0; j < REG; ++j)
            kv[j] = Kp[j * 64 + lane];
        #pragma unroll
        for (int j = 0; j < REG; ++j)
            ev[j] = ((const float2*)(Ww + (size_t)widx[j] * EMB))[lane];

        mx = kv[0].x * ev[0].x;
        my = kv[0].y * ev[0].y;
        #pragma unroll
        for (int j = 1; j < REG; ++j) {
            mx = fmaxf(mx, kv[j].x * ev[j].x);
            my = fmaxf(my, kv[j].y * ev[j].y);
        }
    }

    red[w][2 * lane]     = mx;   // stride-2: 2-way LDS aliasing is free (m136)
    red[w][2 * lane + 1] = my;
    __syncthreads();
    if (tid < EMB) {
        const float s = red[0][tid] + red[1][tid] + red[2][tid] + red[3][tid];
        partial[((size_t)b * NB2 + c4) * EMB + tid] = s;  // every slot written
    }
}

// Kernel 2: one block per batch row. Reduce 127 partials -> noi[128];
// h = relu(noi @ W1 + b1) (1024); logits = h @ W2 + b2 (20);
// softmax + argmax; write logits | prob | cls(as float).
__global__ __launch_bounds__(256) void mlp_kernel(
    const float* __restrict__ partial,
    const float* __restrict__ W1,
    const float* __restrict__ b1,
    const float* __restrict__ W2,
    const float* __restrict__ b2,
    float*       __restrict__ out)
{
    __shared__ float noi[EMB];
    __shared__ float h[2 * ML];
    __shared__ float lg[NC];

    const int b   = blockIdx.x;
    const int tid = threadIdx.x;

    if (tid < EMB) {
        const float* p = partial + (size_t)b * NB2 * EMB + tid;
        float s = 0.f;
        #pragma unroll 8
        for (int k = 0; k < NB2; ++k)
            s += p[(size_t)k * EMB];
        noi[tid] = s;
    }
    __syncthreads();

    // h: each thread owns 4 columns (tid, tid+256, tid+512, tid+768)
    float h0 = b1[tid], h1 = b1[tid + 256], h2 = b1[tid + 512], h3 = b1[tid + 768];
    for (int k = 0; k < EMB; ++k) {
        const float nk = noi[k];
        const float* row = W1 + k * (2 * ML);
        h0 = fmaf(nk, row[tid],       h0);
        h1 = fmaf(nk, row[tid + 256], h1);
        h2 = fmaf(nk, row[tid + 512], h2);
        h3 = fmaf(nk, row[tid + 768], h3);
    }
    h[tid]       = fmaxf(h0, 0.f);
    h[tid + 256] = fmaxf(h1, 0.f);
    h[tid + 512] = fmaxf(h2, 0.f);
    h[tid + 768] = fmaxf(h3, 0.f);
    __syncthreads();

    // logits: wave w handles classes c = w, w+4, ...; lanes split k.
    const int w    = tid >> 6;
    const int lane = tid & 63;
    for (int c = w; c < NC; c += 4) {
        float p = 0.f;
        #pragma unroll 4
        for (int k = lane; k < 2 * ML; k += 64)
            p = fmaf(h[k], W2[k * NC + c], p);
        for (int off = 32; off; off >>= 1)
            p += __shfl_down(p, off);
        if (lane == 0) lg[c] = p + b2[c];
    }
    __syncthreads();

    if (tid == 0) {
        float mx = lg[0];
        for (int c = 1; c < NC; ++c) mx = fmaxf(mx, lg[c]);
        float pr[NC];
        float s = 0.f;
        for (int c = 0; c < NC; ++c) { pr[c] = __expf(lg[c] - mx); s += pr[c]; }
        const float inv = 1.f / s;
        int am = 0; float best = lg[0];
        for (int c = 1; c < NC; ++c) if (lg[c] > best) { best = lg[c]; am = c; }
        for (int c = 0; c < NC; ++c) {
            out[b * NC + c]           = lg[c];           // logits
            out[BB * NC + b * NC + c] = pr[c] * inv;     // prob
        }
        out[2 * BB * NC + b] = (float)am;                // cls (as float)
    }
}

extern "C" void kernel_launch(void* const* d_in, const int* in_sizes, int n_in,
                              void* d_out, int out_size, void* d_ws, size_t ws_size,
                              hipStream_t stream) {
    const int*   train = (const int*)  d_in[0];
    const float* Wr    = (const float*)d_in[1];
    const float* Ww    = (const float*)d_in[2];
    const float* W1    = (const float*)d_in[3];
    const float* b1    = (const float*)d_in[4];
    const float* W2    = (const float*)d_in[5];
    const float* b2    = (const float*)d_in[6];
    float* out     = (float*)d_out;
    float* partial = (float*)d_ws;     // 64*127*128*4 = 4.16 MB

    hipLaunchKernelGGL(noi_kernel, dim3(NB2, BB), dim3(256), 0, stream,
                       train, Wr, Ww, partial);
    hipLaunchKernelGGL(mlp_kernel, dim3(BB), dim3(256), 0, stream,
                       partial, W1, b1, W2, b2, out);
}

// Round 4
// 467.656 us; speedup vs baseline: 1.4441x; 1.0092x over previous
//
#include <hip/hip_runtime.h>
#include <hip/hip_bf16.h>

#define V    100000
#define EMB  128
#define REG  7
#define NC   20
#define ML   512
#define BB   64
#define RAD  3
#define ENT  506      // ML - 2*RAD
#define NBC  64       // chunks of 8 entries per batch row (64*8 = 512 >= 506)

// Kernel 1: 2 entries per wave (half-wave = one entry; 32 lanes x float4 =
// one 512B embedding row slice per load -> 1KB/instruction, fully coalesced).
// Per wave: 8 uniform-ish index loads -> 14 independent float4 loads (14KB in
// flight) -> per-channel max over j -> half-fold via shfl(32) -> 4-wave LDS
// reduce -> partial[128] per block. Straight-line: MLP comes from TLP.
//
// Semantics (reshape trap): E index for (b,i,j) is t=i*7+j;
// word = train[b, (t%506) + (t/506)]; region row = train[b, i+3], slice j.
__global__ __launch_bounds__(256, 4) void noi_kernel(
    const int*   __restrict__ train,
    const float* __restrict__ Wr,
    const float* __restrict__ Ww,
    float*       __restrict__ partial)
{
    __shared__ float red[4][EMB];

    const int b     = blockIdx.y;          // 0..63
    const int chunk = blockIdx.x;          // 0..63 (8 entries each)
    const int tid   = threadIdx.x;
    const int w     = tid >> 6;
    const int lane  = tid & 63;
    const int half  = lane >> 5;           // which entry of the pair
    const int sl    = lane & 31;           // 4-channel group within the row

    const int  i_raw = chunk * 8 + w * 2 + half;
    const bool valid = (i_raw < ENT);
    const int  i     = valid ? i_raw : (ENT - 1);   // clamp; mask result later

    const int* trow = train + b * ML;
    const int  ridx = trow[i + RAD];
    int widx[REG];
    #pragma unroll
    for (int j = 0; j < REG; ++j) {
        const int t = i * REG + j;
        const int r = t / ENT;             // const divisor -> magic mul
        const int e = t - r * ENT;
        widx[j] = trow[e + r];
    }

    const float4* Kp = (const float4*)(Wr + (size_t)ridx * (REG * EMB));
    float4 kv[REG], ev[REG];
    #pragma unroll
    for (int j = 0; j < REG; ++j)
        kv[j] = Kp[j * 32 + sl];
    #pragma unroll
    for (int j = 0; j < REG; ++j)
        ev[j] = ((const float4*)(Ww + (size_t)widx[j] * EMB))[sl];

    float4 m;
    m.x = kv[0].x * ev[0].x;
    m.y = kv[0].y * ev[0].y;
    m.z = kv[0].z * ev[0].z;
    m.w = kv[0].w * ev[0].w;
    #pragma unroll
    for (int j = 1; j < REG; ++j) {
        m.x = fmaxf(m.x, kv[j].x * ev[j].x);
        m.y = fmaxf(m.y, kv[j].y * ev[j].y);
        m.z = fmaxf(m.z, kv[j].z * ev[j].z);
        m.w = fmaxf(m.w, kv[j].w * ev[j].w);
    }
    if (!valid) { m.x = 0.f; m.y = 0.f; m.z = 0.f; m.w = 0.f; }

    // fold the two entries of the wave (sum over i): lane sl += lane sl+32
    m.x += __shfl_down(m.x, 32);
    m.y += __shfl_down(m.y, 32);
    m.z += __shfl_down(m.z, 32);
    m.w += __shfl_down(m.w, 32);
    if (half == 0)
        ((float4*)red[w])[sl] = m;
    __syncthreads();

    if (tid < EMB) {
        const float s = red[0][tid] + red[1][tid] + red[2][tid] + red[3][tid];
        partial[((size_t)b * NBC + chunk) * EMB + tid] = s;   // every slot written
    }
}

// Kernel 2: one block of 1024 threads per batch row (16 waves for latency
// hiding). Reduce 64 partials (8-way parallel) -> noi[128];
// h = relu(noi @ W1 + b1): thread t owns column t, W1 reads fully coalesced;
// logits = h @ W2 + b2 (20); softmax + argmax; write logits | prob | cls.
__global__ __launch_bounds__(1024) void mlp_kernel(
    const float* __restrict__ partial,
    const float* __restrict__ W1,
    const float* __restrict__ b1,
    const float* __restrict__ W2,
    const float* __restrict__ b2,
    float*       __restrict__ out)
{
    __shared__ float red2[8][EMB];
    __shared__ float noi[EMB];
    __shared__ float h[2 * ML];
    __shared__ float lg[NC];

    const int b   = blockIdx.x;
    const int tid = threadIdx.x;

    {   // 8 groups of 128 threads, each sums 8 of the 64 partials
        const int col = tid & 127;
        const int grp = tid >> 7;          // 0..7
        const float* p = partial + ((size_t)b * NBC + grp * 8) * EMB + col;
        float s = 0.f;
        #pragma unroll
        for (int k = 0; k < 8; ++k)
            s += p[(size_t)k * EMB];
        red2[grp][col] = s;
    }
    __syncthreads();
    if (tid < EMB) {
        float s = 0.f;
        #pragma unroll
        for (int g = 0; g < 8; ++g)
            s += red2[g][tid];
        noi[tid] = s;
    }
    __syncthreads();

    // h: thread t owns column t; W1[k*1024 + t] coalesced across the wave
    float acc = b1[tid];
    #pragma unroll 8
    for (int k = 0; k < EMB; ++k)
        acc = fmaf(noi[k], W1[k * (2 * ML) + tid], acc);
    h[tid] = fmaxf(acc, 0.f);
    __syncthreads();

    // logits: 16 waves; wave w takes classes c = w, w+16; lanes split k
    const int w    = tid >> 6;
    const int lane = tid & 63;
    for (int c = w; c < NC; c += 16) {
        float p = 0.f;
        #pragma unroll
        for (int k = lane; k < 2 * ML; k += 64)
            p = fmaf(h[k], W2[k * NC + c], p);
        for (int off = 32; off; off >>= 1)
            p += __shfl_down(p, off);
        if (lane == 0) lg[c] = p + b2[c];
    }
    __syncthreads();

    if (tid == 0) {
        float mx = lg[0];
        for (int c = 1; c < NC; ++c) mx = fmaxf(mx, lg[c]);
        float pr[NC];
        float s = 0.f;
        for (int c = 0; c < NC; ++c) { pr[c] = __expf(lg[c] - mx); s += pr[c]; }
        const float inv = 1.f / s;
        int am = 0; float best = lg[0];
        for (int c = 1; c < NC; ++c) if (lg[c] > best) { best = lg[c]; am = c; }
        for (int c = 0; c < NC; ++c) {
            out[b * NC + c]           = lg[c];           // logits
            out[BB * NC + b * NC + c] = pr[c] * inv;     // prob
        }
        out[2 * BB * NC + b] = (float)am;                // cls (as float)
    }
}

extern "C" void kernel_launch(void* const* d_in, const int* in_sizes, int n_in,
                              void* d_out, int out_size, void* d_ws, size_t ws_size,
                              hipStream_t stream) {
    const int*   train = (const int*)  d_in[0];
    const float* Wr    = (const float*)d_in[1];
    const float* Ww    = (const float*)d_in[2];
    const float* W1    = (const float*)d_in[3];
    const float* b1    = (const float*)d_in[4];
    const float* W2    = (const float*)d_in[5];
    const float* b2    = (const float*)d_in[6];
    float* out     = (float*)d_out;
    float* partial = (float*)d_ws;     // 64*64*128*4 = 2 MB

    hipLaunchKernelGGL(noi_kernel, dim3(NBC, BB), dim3(256), 0, stream,
                       train, Wr, Ww, partial);
    hipLaunchKernelGGL(mlp_kernel, dim3(BB), dim3(1024), 0, stream,
                       partial, W1, b1, W2, b2, out);
}